// Round 4
// baseline (812.628 us; speedup 1.0000x reference)
//
#include <hip/hip_runtime.h>
#include <cstdint>
#include <cstddef>

typedef __attribute__((ext_vector_type(8))) __bf16 bf16x8;
typedef __attribute__((ext_vector_type(4))) __bf16 bf16x4;
typedef __attribute__((ext_vector_type(4))) float f32x4;
typedef __attribute__((ext_vector_type(16))) float f32x16;
typedef __attribute__((ext_vector_type(4))) unsigned uint4v;

#define B_ 4
#define T_ 2048
#define C_ 1024
#define H_ 16
#define D_ 64

__device__ __forceinline__ float fexp2(float x) {
#if __has_builtin(__builtin_amdgcn_exp2f)
  return __builtin_amdgcn_exp2f(x);
#else
  return __expf(x * 0.69314718f);
#endif
}

// ---------------------------------------------------------------- cast f32->bf16
__global__ __launch_bounds__(256) void castk(const float* __restrict__ in,
                                             __bf16* __restrict__ out, int n) {
  int i = (blockIdx.x * blockDim.x + threadIdx.x) * 4;
  if (i >= n) return;
  float4 f = *reinterpret_cast<const float4*>(in + i);
  bf16x4 o;
  o[0] = (__bf16)f.x; o[1] = (__bf16)f.y; o[2] = (__bf16)f.z; o[3] = (__bf16)f.w;
  *reinterpret_cast<bf16x4*>(out + i) = o;
}

// ---------------------------------------------------------------- async global->LDS
__device__ __forceinline__ void gload_lds16(const __bf16* g, __bf16* lds) {
  __builtin_amdgcn_global_load_lds(
      (const __attribute__((address_space(1))) void*)g,
      (__attribute__((address_space(3))) void*)lds, 16, 0, 0);
}

// ---------------------------------------------------------------- GEMM  C = A * Bt^T
// (unchanged — m97 structure, 128x128 tile, BK=64)
template <typename OUTT, bool BIAS>
__device__ __forceinline__ void gemm_bt_body(const __bf16* __restrict__ A,
                                             const __bf16* __restrict__ Bt,
                                             OUTT* __restrict__ Cp,
                                             const float* __restrict__ bias,
                                             int M, int N, int K) {
  constexpr int BK = 64;
  __shared__ __bf16 As[128 * BK];
  __shared__ __bf16 Bs[128 * BK];
  const int tid = threadIdx.x;
  const int w = tid >> 6, l = tid & 63;
  const int wr = w >> 1, wc = w & 1;
  const int lr = l & 15, lg = l >> 4;
  const int m0 = blockIdx.y * 128, n0 = blockIdx.x * 128;
  const int srow = l >> 3, scol = (l & 7) * 8;

  f32x4 acc[4][4] = {};

  for (int k0 = 0; k0 < K; k0 += BK) {
#pragma unroll
    for (int it = 0; it < 4; ++it) {
      const int c = w * 4 + it;
      gload_lds16(A + (size_t)(m0 + 8 * c + srow) * K + k0 + scol, As + c * 512);
      gload_lds16(Bt + (size_t)(n0 + 8 * c + srow) * K + k0 + scol, Bs + c * 512);
    }
    __syncthreads();
    bf16x8 af[4][2], bfv[4][2];
#pragma unroll
    for (int m = 0; m < 4; ++m)
#pragma unroll
      for (int kk = 0; kk < 2; ++kk)
        af[m][kk] = *reinterpret_cast<const bf16x8*>(As + (wr * 64 + m * 16 + lr) * BK + kk * 32 + lg * 8);
#pragma unroll
    for (int n = 0; n < 4; ++n)
#pragma unroll
      for (int kk = 0; kk < 2; ++kk)
        bfv[n][kk] = *reinterpret_cast<const bf16x8*>(Bs + (wc * 64 + n * 16 + lr) * BK + kk * 32 + lg * 8);
#pragma unroll
    for (int kk = 0; kk < 2; ++kk)
#pragma unroll
      for (int m = 0; m < 4; ++m)
#pragma unroll
        for (int n = 0; n < 4; ++n)
          acc[m][n] = __builtin_amdgcn_mfma_f32_16x16x32_bf16(af[m][kk], bfv[n][kk], acc[m][n], 0, 0, 0);
    __syncthreads();
  }
#pragma unroll
  for (int m = 0; m < 4; ++m)
#pragma unroll
    for (int n = 0; n < 4; ++n) {
      const int col = n0 + wc * 64 + n * 16 + lr;
      float bv = 0.f;
      if (BIAS) bv = bias[col];
#pragma unroll
      for (int j = 0; j < 4; ++j) {
        const int row = m0 + wr * 64 + m * 16 + lg * 4 + j;
        Cp[(size_t)row * N + col] = (OUTT)(acc[m][n][j] + bv);
      }
    }
}

__global__ __launch_bounds__(256) void gemm_qkv(const __bf16* __restrict__ xb,
    const __bf16* __restrict__ wq, const __bf16* __restrict__ wk, const __bf16* __restrict__ wv,
    __bf16* __restrict__ q, __bf16* __restrict__ k, __bf16* __restrict__ v) {
  const __bf16* W = (blockIdx.z == 0) ? wq : (blockIdx.z == 1) ? wk : wv;
  __bf16* O = (blockIdx.z == 0) ? q : (blockIdx.z == 1) ? k : v;
  gemm_bt_body<__bf16, false>(xb, W, O, nullptr, B_ * T_, C_, C_);
}

__global__ __launch_bounds__(256) void gemm_proj(const __bf16* __restrict__ ao,
    const __bf16* __restrict__ wp, float* __restrict__ out, const float* __restrict__ bp) {
  gemm_bt_body<float, true>(ao, wp, out, bp, B_ * T_, C_, C_);
}

// ---------------------------------------------------------------- V transpose
// v [B*T][C] (col = h*64+d)  ->  vt [B][H][D][T].
__global__ __launch_bounds__(256) void transposeV(const __bf16* __restrict__ v,
                                                  __bf16* __restrict__ vt) {
  __shared__ __bf16 tile[64][72];
  const int t0 = blockIdx.x * 64;
  const int h = blockIdx.y, b = blockIdx.z;
  const int l = threadIdx.x;
  const int r = l >> 2, c8 = (l & 3) * 16;
  const __bf16* src = v + (size_t)(b * T_ + t0 + r) * C_ + h * 64 + c8;
  *reinterpret_cast<bf16x8*>(&tile[r][c8]) = *reinterpret_cast<const bf16x8*>(src);
  *reinterpret_cast<bf16x8*>(&tile[r][c8 + 8]) = *reinterpret_cast<const bf16x8*>(src + 8);
  __syncthreads();
  __bf16* dst = vt + (size_t)((b * H_ + h) * 64 + r) * T_ + t0 + c8;
  bf16x8 o0, o1;
#pragma unroll
  for (int i = 0; i < 8; ++i) { o0[i] = tile[c8 + i][r]; o1[i] = tile[c8 + 8 + i][r]; }
  *reinterpret_cast<bf16x8*>(dst) = o0;
  *reinterpret_cast<bf16x8*>(dst + 8) = o1;
}

// ---------------------------------------------------------------- helpers
__device__ __forceinline__ unsigned pk2(float a, float b) {
  const unsigned short ua = __builtin_bit_cast(unsigned short, (__bf16)a);
  const unsigned short ub = __builtin_bit_cast(unsigned short, (__bf16)b);
  return (unsigned)ua | ((unsigned)ub << 16);
}

// ---------------------------------------------------------------- flash attention v4
// One q-block (32 rows) per wave, LPT dispatch order, K double-buffer prefetch,
// V issued early (hides under softmax), exp2-direct softmax, setprio on MFMA.
// Layout notes as v3 (R3-verified): swapped QK^T -> S^T col=q=lane31,
// row kv=(r&3)+8*(r>>2)+4*hi; P^T frags via shfl_xor(32); O^T = V^T * P^T.
__global__ __launch_bounds__(256, 4) void attn_fwd(const __bf16* __restrict__ qb,
                                                   const __bf16* __restrict__ kb,
                                                   const __bf16* __restrict__ vt,
                                                   __bf16* __restrict__ ao) {
  const int tid = threadIdx.x;
  const int w = tid >> 6, l = tid & 63;
  const int lane31 = l & 31, hi = l >> 5;
  const int b = blockIdx.y >> 4;
  const int qx = 63 - (blockIdx.x * 4 + w);  // LPT: longest q-blocks first
  const int qg = qx * 32;
  const int ntiles = qx + 1;
  const size_t rowbase = (size_t)b * T_;
  const int hoff = (blockIdx.y & 15) * D_;
  const __bf16* vtb = vt + (size_t)blockIdx.y * (size_t)(D_ * T_);
  const float K2 = 0.04508422f;   // C^-0.5 * log2(e)
  const float THRRAW = 177.0f;    // defer-max: exp2 arg <= 8 -> P <= 256

  // Q fragments (B-operand): lane holds Q[qg+lane31][t4*16 + hi*8 + e]
  bf16x8 qf[4];
  {
    const __bf16* qp = qb + (rowbase + qg + lane31) * C_ + hoff + hi * 8;
#pragma unroll
    for (int t4 = 0; t4 < 4; ++t4) qf[t4] = *reinterpret_cast<const bf16x8*>(qp + t4 * 16);
  }

  f32x16 acc0 = {};  // O^T rows d 0..31 (col = q = lane31)
  f32x16 acc1 = {};  // O^T rows d 32..63
  float m_run = -3.0e38f, l_run = 0.f;

  auto loadK = [&](int t, bf16x8 (&kf)[4]) {
    const __bf16* kp = kb + (rowbase + t * 32 + lane31) * C_ + hoff + hi * 8;
#pragma unroll
    for (int t4 = 0; t4 < 4; ++t4) kf[t4] = *reinterpret_cast<const bf16x8*>(kp + t4 * 16);
  };
  auto loadV = [&](int t, bf16x8 (&vf)[4]) {
    const __bf16* vp = vtb + (size_t)lane31 * T_ + t * 32 + hi * 8;
#pragma unroll
    for (int dblk = 0; dblk < 2; ++dblk)
#pragma unroll
      for (int ks = 0; ks < 2; ++ks)
        vf[dblk * 2 + ks] = *reinterpret_cast<const bf16x8*>(vp + dblk * 32 * T_ + ks * 16);
  };

  auto tile = [&](const bf16x8 (&kf)[4], const bf16x8 (&vf)[4], bool mask) {
    // S^T[kv][q] = K * Q^T
    f32x16 s = {};
    __builtin_amdgcn_s_setprio(1);
#pragma unroll
    for (int t4 = 0; t4 < 4; ++t4)
      s = __builtin_amdgcn_mfma_f32_32x32x16_bf16(kf[t4], qf[t4], s, 0, 0, 0);
    __builtin_amdgcn_s_setprio(0);

    float sv[16];
#pragma unroll
    for (int r = 0; r < 16; ++r) sv[r] = s[r];
    if (mask) {  // diagonal tile: kv_local <= q_local
#pragma unroll
      for (int r = 0; r < 16; ++r) {
        const int kvloc = (r & 3) + 8 * (r >> 2) + 4 * hi;
        sv[r] = (kvloc <= lane31) ? sv[r] : -1e30f;
      }
    }
    // tree max (dep depth 4)
    float a8[8];
#pragma unroll
    for (int r = 0; r < 8; ++r) a8[r] = fmaxf(sv[2 * r], sv[2 * r + 1]);
#pragma unroll
    for (int r = 0; r < 4; ++r) a8[r] = fmaxf(a8[2 * r], a8[2 * r + 1]);
    float mm = fmaxf(fmaxf(a8[0], a8[1]), fmaxf(a8[2], a8[3]));
    mm = fmaxf(mm, __shfl_xor(mm, 32));
    if (mm > m_run + THRRAW) {  // defer-max (T13)
      const float alpha = fexp2((m_run - mm) * K2);
#pragma unroll
      for (int r = 0; r < 16; ++r) { acc0[r] *= alpha; acc1[r] *= alpha; }
      l_run *= alpha;
      m_run = mm;
    }
    const float negm = -m_run * K2;
#pragma unroll
    for (int r = 0; r < 16; ++r)
      sv[r] = fexp2(__builtin_fmaf(sv[r], K2, negm));
    // tree sum
    float b8[8];
#pragma unroll
    for (int r = 0; r < 8; ++r) b8[r] = sv[2 * r] + sv[2 * r + 1];
#pragma unroll
    for (int r = 0; r < 4; ++r) b8[r] = b8[2 * r] + b8[2 * r + 1];
    float rs = (b8[0] + b8[1]) + (b8[2] + b8[3]);
    rs += __shfl_xor(rs, 32);
    l_run += rs;

    // P^T B-fragments via shfl (R3-verified mapping)
    unsigned pwv[8];
#pragma unroll
    for (int ks = 0; ks < 2; ++ks) {
      const unsigned X0 = pk2(sv[ks * 8 + 0], sv[ks * 8 + 1]);
      const unsigned X1 = pk2(sv[ks * 8 + 2], sv[ks * 8 + 3]);
      const unsigned Y0 = pk2(sv[ks * 8 + 4], sv[ks * 8 + 5]);
      const unsigned Y1 = pk2(sv[ks * 8 + 6], sv[ks * 8 + 7]);
      const unsigned sX0 = __shfl_xor(X0, 32);
      const unsigned sX1 = __shfl_xor(X1, 32);
      const unsigned sY0 = __shfl_xor(Y0, 32);
      const unsigned sY1 = __shfl_xor(Y1, 32);
      pwv[ks * 4 + 0] = hi ? sY0 : X0;
      pwv[ks * 4 + 1] = hi ? sY1 : X1;
      pwv[ks * 4 + 2] = hi ? Y0 : sX0;
      pwv[ks * 4 + 3] = hi ? Y1 : sX1;
    }
    const uint4v u0 = {pwv[0], pwv[1], pwv[2], pwv[3]};
    const uint4v u1 = {pwv[4], pwv[5], pwv[6], pwv[7]};
    const bf16x8 pf0 = __builtin_bit_cast(bf16x8, u0);
    const bf16x8 pf1 = __builtin_bit_cast(bf16x8, u1);

    __builtin_amdgcn_s_setprio(1);
    acc0 = __builtin_amdgcn_mfma_f32_32x32x16_bf16(vf[0], pf0, acc0, 0, 0, 0);
    acc0 = __builtin_amdgcn_mfma_f32_32x32x16_bf16(vf[1], pf1, acc0, 0, 0, 0);
    acc1 = __builtin_amdgcn_mfma_f32_32x32x16_bf16(vf[2], pf0, acc1, 0, 0, 0);
    acc1 = __builtin_amdgcn_mfma_f32_32x32x16_bf16(vf[3], pf1, acc1, 0, 0, 0);
    __builtin_amdgcn_s_setprio(0);
  };

  bf16x8 kA[4], kB[4], vf[4];
  loadK(0, kA);
  int t = 0;
  for (; t + 1 < ntiles; ++t) {
    loadV(t, vf);              // current V: latency hides under QK^T + softmax
    if ((t & 1) == 0) { loadK(t + 1, kB); tile(kA, vf, false); }
    else              { loadK(t + 1, kA); tile(kB, vf, false); }
  }
  loadV(t, vf);
  if ((t & 1) == 0) tile(kA, vf, true);
  else              tile(kB, vf, true);

  // epilogue: O[q][d] = O^T[d][q]/l ; d = dblk*32 + qd*8 + hi*4 + j
  const float rl = 1.0f / l_run;
  __bf16* op = ao + (rowbase + qg + lane31) * C_ + hoff + hi * 4;
#pragma unroll
  for (int dblk = 0; dblk < 2; ++dblk)
#pragma unroll
    for (int qd = 0; qd < 4; ++qd) {
      bf16x4 ov;
#pragma unroll
      for (int j = 0; j < 4; ++j) {
        const float av = (dblk == 0) ? acc0[qd * 4 + j] : acc1[qd * 4 + j];
        ov[j] = (__bf16)(av * rl);
      }
      *reinterpret_cast<bf16x4*>(op + dblk * 32 + qd * 8) = ov;
    }
}

// ---------------------------------------------------------------- launch
extern "C" void kernel_launch(void* const* d_in, const int* in_sizes, int n_in,
                              void* d_out, int out_size, void* d_ws, size_t ws_size,
                              hipStream_t stream) {
  const float* x  = (const float*)d_in[0];
  const float* Wq = (const float*)d_in[1];
  const float* Wk = (const float*)d_in[2];
  const float* Wv = (const float*)d_in[3];
  const float* Wp = (const float*)d_in[4];
  const float* bp = (const float*)d_in[5];
  float* out = (float*)d_out;

  const int NX = B_ * T_ * C_;
  const int NW = C_ * C_;

  __bf16* xb  = (__bf16*)d_ws;
  __bf16* wqb = xb + NX;
  __bf16* wkb = wqb + NW;
  __bf16* wvb = wkb + NW;
  __bf16* wpb = wvb + NW;
  __bf16* qb  = wpb + NW;
  __bf16* kb  = qb + NX;
  __bf16* vb  = kb + NX;
  __bf16* aob = vb + NX;
  __bf16* vtb = xb;  // xb dead after gemm_qkv; reuse as V^T [B][H][D][T]

  castk<<<NX / 1024, 256, 0, stream>>>(x, xb, NX);
  castk<<<NW / 1024, 256, 0, stream>>>(Wq, wqb, NW);
  castk<<<NW / 1024, 256, 0, stream>>>(Wk, wkb, NW);
  castk<<<NW / 1024, 256, 0, stream>>>(Wv, wvb, NW);
  castk<<<NW / 1024, 256, 0, stream>>>(Wp, wpb, NW);

  gemm_qkv<<<dim3(C_ / 128, (B_ * T_) / 128, 3), 256, 0, stream>>>(xb, wqb, wkb, wvb, qb, kb, vb);
  transposeV<<<dim3(T_ / 64, H_, B_), 256, 0, stream>>>(vb, vtb);
  attn_fwd<<<dim3(16, B_ * H_), 256, 0, stream>>>(qb, kb, vtb, aob);
  gemm_proj<<<dim3(C_ / 128, (B_ * T_) / 128), 256, 0, stream>>>(aob, wpb, out, bp);
}

// Round 5
// 395.439 us; speedup vs baseline: 2.0550x; 2.0550x over previous
//
#include <hip/hip_runtime.h>
#include <cstdint>
#include <cstddef>

typedef __attribute__((ext_vector_type(8))) __bf16 bf16x8;
typedef __attribute__((ext_vector_type(4))) __bf16 bf16x4;
typedef __attribute__((ext_vector_type(4))) float f32x4;
typedef __attribute__((ext_vector_type(16))) float f32x16;
typedef __attribute__((ext_vector_type(4))) unsigned uint4v;

#define B_ 4
#define T_ 2048
#define C_ 1024
#define H_ 16
#define D_ 64

__device__ __forceinline__ float fexp2(float x) {
#if __has_builtin(__builtin_amdgcn_exp2f)
  return __builtin_amdgcn_exp2f(x);
#else
  return __expf(x * 0.69314718f);
#endif
}

// ---------------------------------------------------------------- cast f32->bf16
__global__ __launch_bounds__(256) void castk(const float* __restrict__ in,
                                             __bf16* __restrict__ out, int n) {
  int i = (blockIdx.x * blockDim.x + threadIdx.x) * 4;
  if (i >= n) return;
  float4 f = *reinterpret_cast<const float4*>(in + i);
  bf16x4 o;
  o[0] = (__bf16)f.x; o[1] = (__bf16)f.y; o[2] = (__bf16)f.z; o[3] = (__bf16)f.w;
  *reinterpret_cast<bf16x4*>(out + i) = o;
}

// ---------------------------------------------------------------- async global->LDS
__device__ __forceinline__ void gload_lds16(const __bf16* g, __bf16* lds) {
  __builtin_amdgcn_global_load_lds(
      (const __attribute__((address_space(1))) void*)g,
      (__attribute__((address_space(3))) void*)lds, 16, 0, 0);
}

// ---------------------------------------------------------------- GEMM  C = A * Bt^T
// (unchanged — m97 structure, 128x128 tile, BK=64)
template <typename OUTT, bool BIAS>
__device__ __forceinline__ void gemm_bt_body(const __bf16* __restrict__ A,
                                             const __bf16* __restrict__ Bt,
                                             OUTT* __restrict__ Cp,
                                             const float* __restrict__ bias,
                                             int M, int N, int K) {
  constexpr int BK = 64;
  __shared__ __bf16 As[128 * BK];
  __shared__ __bf16 Bs[128 * BK];
  const int tid = threadIdx.x;
  const int w = tid >> 6, l = tid & 63;
  const int wr = w >> 1, wc = w & 1;
  const int lr = l & 15, lg = l >> 4;
  const int m0 = blockIdx.y * 128, n0 = blockIdx.x * 128;
  const int srow = l >> 3, scol = (l & 7) * 8;

  f32x4 acc[4][4] = {};

  for (int k0 = 0; k0 < K; k0 += BK) {
#pragma unroll
    for (int it = 0; it < 4; ++it) {
      const int c = w * 4 + it;
      gload_lds16(A + (size_t)(m0 + 8 * c + srow) * K + k0 + scol, As + c * 512);
      gload_lds16(Bt + (size_t)(n0 + 8 * c + srow) * K + k0 + scol, Bs + c * 512);
    }
    __syncthreads();
    bf16x8 af[4][2], bfv[4][2];
#pragma unroll
    for (int m = 0; m < 4; ++m)
#pragma unroll
      for (int kk = 0; kk < 2; ++kk)
        af[m][kk] = *reinterpret_cast<const bf16x8*>(As + (wr * 64 + m * 16 + lr) * BK + kk * 32 + lg * 8);
#pragma unroll
    for (int n = 0; n < 4; ++n)
#pragma unroll
      for (int kk = 0; kk < 2; ++kk)
        bfv[n][kk] = *reinterpret_cast<const bf16x8*>(Bs + (wc * 64 + n * 16 + lr) * BK + kk * 32 + lg * 8);
#pragma unroll
    for (int kk = 0; kk < 2; ++kk)
#pragma unroll
      for (int m = 0; m < 4; ++m)
#pragma unroll
        for (int n = 0; n < 4; ++n)
          acc[m][n] = __builtin_amdgcn_mfma_f32_16x16x32_bf16(af[m][kk], bfv[n][kk], acc[m][n], 0, 0, 0);
    __syncthreads();
  }
#pragma unroll
  for (int m = 0; m < 4; ++m)
#pragma unroll
    for (int n = 0; n < 4; ++n) {
      const int col = n0 + wc * 64 + n * 16 + lr;
      float bv = 0.f;
      if (BIAS) bv = bias[col];
#pragma unroll
      for (int j = 0; j < 4; ++j) {
        const int row = m0 + wr * 64 + m * 16 + lg * 4 + j;
        Cp[(size_t)row * N + col] = (OUTT)(acc[m][n][j] + bv);
      }
    }
}

__global__ __launch_bounds__(256) void gemm_qkv(const __bf16* __restrict__ xb,
    const __bf16* __restrict__ wq, const __bf16* __restrict__ wk, const __bf16* __restrict__ wv,
    __bf16* __restrict__ q, __bf16* __restrict__ k, __bf16* __restrict__ v) {
  const __bf16* W = (blockIdx.z == 0) ? wq : (blockIdx.z == 1) ? wk : wv;
  __bf16* O = (blockIdx.z == 0) ? q : (blockIdx.z == 1) ? k : v;
  gemm_bt_body<__bf16, false>(xb, W, O, nullptr, B_ * T_, C_, C_);
}

__global__ __launch_bounds__(256) void gemm_proj(const __bf16* __restrict__ ao,
    const __bf16* __restrict__ wp, float* __restrict__ out, const float* __restrict__ bp) {
  gemm_bt_body<float, true>(ao, wp, out, bp, B_ * T_, C_, C_);
}

// ---------------------------------------------------------------- V transpose
// v [B*T][C] (col = h*64+d)  ->  vt [B][H][D][T].
__global__ __launch_bounds__(256) void transposeV(const __bf16* __restrict__ v,
                                                  __bf16* __restrict__ vt) {
  __shared__ __bf16 tile[64][72];
  const int t0 = blockIdx.x * 64;
  const int h = blockIdx.y, b = blockIdx.z;
  const int l = threadIdx.x;
  const int r = l >> 2, c8 = (l & 3) * 16;
  const __bf16* src = v + (size_t)(b * T_ + t0 + r) * C_ + h * 64 + c8;
  *reinterpret_cast<bf16x8*>(&tile[r][c8]) = *reinterpret_cast<const bf16x8*>(src);
  *reinterpret_cast<bf16x8*>(&tile[r][c8 + 8]) = *reinterpret_cast<const bf16x8*>(src + 8);
  __syncthreads();
  __bf16* dst = vt + (size_t)((b * H_ + h) * 64 + r) * T_ + t0 + c8;
  bf16x8 o0, o1;
#pragma unroll
  for (int i = 0; i < 8; ++i) { o0[i] = tile[c8 + i][r]; o1[i] = tile[c8 + 8 + i][r]; }
  *reinterpret_cast<bf16x8*>(dst) = o0;
  *reinterpret_cast<bf16x8*>(dst + 8) = o1;
}

// ---------------------------------------------------------------- helpers
__device__ __forceinline__ unsigned pk2(float a, float b) {
  const unsigned short ua = __builtin_bit_cast(unsigned short, (__bf16)a);
  const unsigned short ub = __builtin_bit_cast(unsigned short, (__bf16)b);
  return (unsigned)ua | ((unsigned)ub << 16);
}

// ---------------------------------------------------------------- flash attention v5
// R3 structure (inline, proven) + one q-block/wave (2x TLP, LPT order) +
// exp2-direct softmax + tree reductions + setprio on MFMA clusters.
// Layouts (R3-verified): swapped QK^T -> S^T col=q=lane31, row kv=(r&3)+8*(r>>2)+4*hi;
// P^T frags via shfl_xor(32); O^T = V^T * P^T from pre-transposed global V^T.
__global__ __launch_bounds__(256) void attn_fwd(const __bf16* __restrict__ qb,
                                                const __bf16* __restrict__ kb,
                                                const __bf16* __restrict__ vt,
                                                __bf16* __restrict__ ao) {
  const int tid = threadIdx.x;
  const int w = tid >> 6, l = tid & 63;
  const int lane31 = l & 31, hi = l >> 5;
  const int b = blockIdx.y >> 4;
  const int qx = 63 - (blockIdx.x * 4 + w);  // LPT: longest q-blocks first
  const int qg = qx * 32;
  const int ntiles = qx + 1;
  const size_t rowbase = (size_t)b * T_;
  const int hoff = (blockIdx.y & 15) * D_;
  const __bf16* vtb = vt + (size_t)blockIdx.y * (size_t)(D_ * T_);
  const float K2 = 0.04508422f;   // C^-0.5 * log2(e)
  const float THRRAW = 177.0f;    // defer-max: exp2 arg <= 8 -> P <= 256

  // Q fragments (B-operand): lane holds Q[qg+lane31][t4*16 + hi*8 + e]
  bf16x8 qf[4];
  {
    const __bf16* qp = qb + (rowbase + qg + lane31) * C_ + hoff + hi * 8;
#pragma unroll
    for (int t4 = 0; t4 < 4; ++t4) qf[t4] = *reinterpret_cast<const bf16x8*>(qp + t4 * 16);
  }

  f32x16 acc0 = {};  // O^T rows d 0..31 (col = q = lane31)
  f32x16 acc1 = {};  // O^T rows d 32..63
  float m_run = -3.0e38f, l_run = 0.f;

  for (int t = 0; t < ntiles; ++t) {
    const int kv0 = t * 32;
    // K fragments (A-operand): lane holds K[kv0+lane31][t4*16 + hi*8 + e]
    const __bf16* kp = kb + (rowbase + kv0 + lane31) * C_ + hoff + hi * 8;
    bf16x8 kf[4];
#pragma unroll
    for (int t4 = 0; t4 < 4; ++t4)
      kf[t4] = *reinterpret_cast<const bf16x8*>(kp + t4 * 16);
    // V^T fragments (A-operand of PV): lane holds VT[dblk*32+lane31][kv0+ks*16+hi*8+e]
    const __bf16* vp = vtb + (size_t)lane31 * T_ + kv0 + hi * 8;
    bf16x8 vf[2][2];
#pragma unroll
    for (int dblk = 0; dblk < 2; ++dblk)
#pragma unroll
      for (int ks = 0; ks < 2; ++ks)
        vf[dblk][ks] = *reinterpret_cast<const bf16x8*>(vp + dblk * 32 * T_ + ks * 16);

    // S^T[kv][q] = K * Q^T
    f32x16 s = {};
    __builtin_amdgcn_s_setprio(1);
#pragma unroll
    for (int t4 = 0; t4 < 4; ++t4)
      s = __builtin_amdgcn_mfma_f32_32x32x16_bf16(kf[t4], qf[t4], s, 0, 0, 0);
    __builtin_amdgcn_s_setprio(0);

    float sv[16];
#pragma unroll
    for (int r = 0; r < 16; ++r) sv[r] = s[r];
    if (t == ntiles - 1) {  // diagonal tile: kv_local <= q_local
#pragma unroll
      for (int r = 0; r < 16; ++r) {
        const int kvloc = (r & 3) + 8 * (r >> 2) + 4 * hi;
        sv[r] = (kvloc <= lane31) ? sv[r] : -1e30f;
      }
    }

    // tree max (dep depth 4)
    float a8[8];
#pragma unroll
    for (int r = 0; r < 8; ++r) a8[r] = fmaxf(sv[2 * r], sv[2 * r + 1]);
#pragma unroll
    for (int r = 0; r < 4; ++r) a8[r] = fmaxf(a8[2 * r], a8[2 * r + 1]);
    float mm = fmaxf(fmaxf(a8[0], a8[1]), fmaxf(a8[2], a8[3]));
    mm = fmaxf(mm, __shfl_xor(mm, 32));
    if (mm > m_run + THRRAW) {  // defer-max (T13)
      const float alpha = fexp2((m_run - mm) * K2);
#pragma unroll
      for (int r = 0; r < 16; ++r) { acc0[r] *= alpha; acc1[r] *= alpha; }
      l_run *= alpha;
      m_run = mm;
    }
    const float negm = -m_run * K2;
#pragma unroll
    for (int r = 0; r < 16; ++r)
      sv[r] = fexp2(__builtin_fmaf(sv[r], K2, negm));
    // tree sum
    float b8[8];
#pragma unroll
    for (int r = 0; r < 8; ++r) b8[r] = sv[2 * r] + sv[2 * r + 1];
#pragma unroll
    for (int r = 0; r < 4; ++r) b8[r] = b8[2 * r] + b8[2 * r + 1];
    float rs = (b8[0] + b8[1]) + (b8[2] + b8[3]);
    rs += __shfl_xor(rs, 32);
    l_run += rs;

    // P^T B-fragments via shfl (R3-verified mapping)
    unsigned pwv[8];
#pragma unroll
    for (int ks = 0; ks < 2; ++ks) {
      const unsigned X0 = pk2(sv[ks * 8 + 0], sv[ks * 8 + 1]);
      const unsigned X1 = pk2(sv[ks * 8 + 2], sv[ks * 8 + 3]);
      const unsigned Y0 = pk2(sv[ks * 8 + 4], sv[ks * 8 + 5]);
      const unsigned Y1 = pk2(sv[ks * 8 + 6], sv[ks * 8 + 7]);
      const unsigned sX0 = __shfl_xor(X0, 32);
      const unsigned sX1 = __shfl_xor(X1, 32);
      const unsigned sY0 = __shfl_xor(Y0, 32);
      const unsigned sY1 = __shfl_xor(Y1, 32);
      pwv[ks * 4 + 0] = hi ? sY0 : X0;
      pwv[ks * 4 + 1] = hi ? sY1 : X1;
      pwv[ks * 4 + 2] = hi ? Y0 : sX0;
      pwv[ks * 4 + 3] = hi ? Y1 : sX1;
    }
    const uint4v u0 = {pwv[0], pwv[1], pwv[2], pwv[3]};
    const uint4v u1 = {pwv[4], pwv[5], pwv[6], pwv[7]};
    const bf16x8 pf0 = __builtin_bit_cast(bf16x8, u0);
    const bf16x8 pf1 = __builtin_bit_cast(bf16x8, u1);

    // O^T += V^T * P^T
    __builtin_amdgcn_s_setprio(1);
    acc0 = __builtin_amdgcn_mfma_f32_32x32x16_bf16(vf[0][0], pf0, acc0, 0, 0, 0);
    acc0 = __builtin_amdgcn_mfma_f32_32x32x16_bf16(vf[0][1], pf1, acc0, 0, 0, 0);
    acc1 = __builtin_amdgcn_mfma_f32_32x32x16_bf16(vf[1][0], pf0, acc1, 0, 0, 0);
    acc1 = __builtin_amdgcn_mfma_f32_32x32x16_bf16(vf[1][1], pf1, acc1, 0, 0, 0);
    __builtin_amdgcn_s_setprio(0);
  }

  // epilogue: O[q][d] = O^T[d][q]/l ; d = dblk*32 + qd*8 + hi*4 + j
  const float rl = 1.0f / l_run;
  __bf16* op = ao + (rowbase + qg + lane31) * C_ + hoff + hi * 4;
#pragma unroll
  for (int dblk = 0; dblk < 2; ++dblk)
#pragma unroll
    for (int qd = 0; qd < 4; ++qd) {
      bf16x4 ov;
#pragma unroll
      for (int j = 0; j < 4; ++j) {
        const float av = (dblk == 0) ? acc0[qd * 4 + j] : acc1[qd * 4 + j];
        ov[j] = (__bf16)(av * rl);
      }
      *reinterpret_cast<bf16x4*>(op + dblk * 32 + qd * 8) = ov;
    }
}

// ---------------------------------------------------------------- launch
extern "C" void kernel_launch(void* const* d_in, const int* in_sizes, int n_in,
                              void* d_out, int out_size, void* d_ws, size_t ws_size,
                              hipStream_t stream) {
  const float* x  = (const float*)d_in[0];
  const float* Wq = (const float*)d_in[1];
  const float* Wk = (const float*)d_in[2];
  const float* Wv = (const float*)d_in[3];
  const float* Wp = (const float*)d_in[4];
  const float* bp = (const float*)d_in[5];
  float* out = (float*)d_out;

  const int NX = B_ * T_ * C_;
  const int NW = C_ * C_;

  __bf16* xb  = (__bf16*)d_ws;
  __bf16* wqb = xb + NX;
  __bf16* wkb = wqb + NW;
  __bf16* wvb = wkb + NW;
  __bf16* wpb = wvb + NW;
  __bf16* qb  = wpb + NW;
  __bf16* kb  = qb + NX;
  __bf16* vb  = kb + NX;
  __bf16* aob = vb + NX;
  __bf16* vtb = xb;  // xb dead after gemm_qkv; reuse as V^T [B][H][D][T]

  castk<<<NX / 1024, 256, 0, stream>>>(x, xb, NX);
  castk<<<NW / 1024, 256, 0, stream>>>(Wq, wqb, NW);
  castk<<<NW / 1024, 256, 0, stream>>>(Wk, wkb, NW);
  castk<<<NW / 1024, 256, 0, stream>>>(Wv, wvb, NW);
  castk<<<NW / 1024, 256, 0, stream>>>(Wp, wpb, NW);

  gemm_qkv<<<dim3(C_ / 128, (B_ * T_) / 128, 3), 256, 0, stream>>>(xb, wqb, wkb, wvb, qb, kb, vb);
  transposeV<<<dim3(T_ / 64, H_, B_), 256, 0, stream>>>(vb, vtb);
  attn_fwd<<<dim3(16, B_ * H_), 256, 0, stream>>>(qb, kb, vtb, aob);
  gemm_proj<<<dim3(C_ / 128, (B_ * T_) / 128), 256, 0, stream>>>(aob, wpb, out, bp);
}

// Round 6
// 264.192 us; speedup vs baseline: 3.0759x; 1.4968x over previous
//
#include <hip/hip_runtime.h>
#include <cstdint>
#include <cstddef>

typedef __attribute__((ext_vector_type(8))) __bf16 bf16x8;
typedef __attribute__((ext_vector_type(4))) __bf16 bf16x4;
typedef __attribute__((ext_vector_type(4))) float f32x4;
typedef __attribute__((ext_vector_type(16))) float f32x16;
typedef __attribute__((ext_vector_type(4))) unsigned uint4v;

#define B_ 4
#define T_ 2048
#define C_ 1024
#define H_ 16
#define D_ 64

__device__ __forceinline__ float fexp2(float x) {
#if __has_builtin(__builtin_amdgcn_exp2f)
  return __builtin_amdgcn_exp2f(x);
#else
  return __expf(x * 0.69314718f);
#endif
}

// ---------------------------------------------------------------- cast f32->bf16
__global__ __launch_bounds__(256) void castk(const float* __restrict__ in,
                                             __bf16* __restrict__ out, int n) {
  int i = (blockIdx.x * blockDim.x + threadIdx.x) * 4;
  if (i >= n) return;
  float4 f = *reinterpret_cast<const float4*>(in + i);
  bf16x4 o;
  o[0] = (__bf16)f.x; o[1] = (__bf16)f.y; o[2] = (__bf16)f.z; o[3] = (__bf16)f.w;
  *reinterpret_cast<bf16x4*>(out + i) = o;
}

// ---------------------------------------------------------------- async global->LDS
__device__ __forceinline__ void gload_lds16(const __bf16* g, __bf16* lds) {
  __builtin_amdgcn_global_load_lds(
      (const __attribute__((address_space(1))) void*)g,
      (__attribute__((address_space(3))) void*)lds, 16, 0, 0);
}

// ---------------------------------------------------------------- GEMM  C = A * Bt^T
// (unchanged — m97 structure, 128x128 tile, BK=64)
template <typename OUTT, bool BIAS>
__device__ __forceinline__ void gemm_bt_body(const __bf16* __restrict__ A,
                                             const __bf16* __restrict__ Bt,
                                             OUTT* __restrict__ Cp,
                                             const float* __restrict__ bias,
                                             int M, int N, int K) {
  constexpr int BK = 64;
  __shared__ __bf16 As[128 * BK];
  __shared__ __bf16 Bs[128 * BK];
  const int tid = threadIdx.x;
  const int w = tid >> 6, l = tid & 63;
  const int wr = w >> 1, wc = w & 1;
  const int lr = l & 15, lg = l >> 4;
  const int m0 = blockIdx.y * 128, n0 = blockIdx.x * 128;
  const int srow = l >> 3, scol = (l & 7) * 8;

  f32x4 acc[4][4] = {};

  for (int k0 = 0; k0 < K; k0 += BK) {
#pragma unroll
    for (int it = 0; it < 4; ++it) {
      const int c = w * 4 + it;
      gload_lds16(A + (size_t)(m0 + 8 * c + srow) * K + k0 + scol, As + c * 512);
      gload_lds16(Bt + (size_t)(n0 + 8 * c + srow) * K + k0 + scol, Bs + c * 512);
    }
    __syncthreads();
    bf16x8 af[4][2], bfv[4][2];
#pragma unroll
    for (int m = 0; m < 4; ++m)
#pragma unroll
      for (int kk = 0; kk < 2; ++kk)
        af[m][kk] = *reinterpret_cast<const bf16x8*>(As + (wr * 64 + m * 16 + lr) * BK + kk * 32 + lg * 8);
#pragma unroll
    for (int n = 0; n < 4; ++n)
#pragma unroll
      for (int kk = 0; kk < 2; ++kk)
        bfv[n][kk] = *reinterpret_cast<const bf16x8*>(Bs + (wc * 64 + n * 16 + lr) * BK + kk * 32 + lg * 8);
#pragma unroll
    for (int kk = 0; kk < 2; ++kk)
#pragma unroll
      for (int m = 0; m < 4; ++m)
#pragma unroll
        for (int n = 0; n < 4; ++n)
          acc[m][n] = __builtin_amdgcn_mfma_f32_16x16x32_bf16(af[m][kk], bfv[n][kk], acc[m][n], 0, 0, 0);
    __syncthreads();
  }
#pragma unroll
  for (int m = 0; m < 4; ++m)
#pragma unroll
    for (int n = 0; n < 4; ++n) {
      const int col = n0 + wc * 64 + n * 16 + lr;
      float bv = 0.f;
      if (BIAS) bv = bias[col];
#pragma unroll
      for (int j = 0; j < 4; ++j) {
        const int row = m0 + wr * 64 + m * 16 + lg * 4 + j;
        Cp[(size_t)row * N + col] = (OUTT)(acc[m][n][j] + bv);
      }
    }
}

__global__ __launch_bounds__(256) void gemm_qkv(const __bf16* __restrict__ xb,
    const __bf16* __restrict__ wq, const __bf16* __restrict__ wk, const __bf16* __restrict__ wv,
    __bf16* __restrict__ q, __bf16* __restrict__ k, __bf16* __restrict__ v) {
  const __bf16* W = (blockIdx.z == 0) ? wq : (blockIdx.z == 1) ? wk : wv;
  __bf16* O = (blockIdx.z == 0) ? q : (blockIdx.z == 1) ? k : v;
  gemm_bt_body<__bf16, false>(xb, W, O, nullptr, B_ * T_, C_, C_);
}

__global__ __launch_bounds__(256) void gemm_proj(const __bf16* __restrict__ ao,
    const __bf16* __restrict__ wp, float* __restrict__ out, const float* __restrict__ bp) {
  gemm_bt_body<float, true>(ao, wp, out, bp, B_ * T_, C_, C_);
}

// ---------------------------------------------------------------- V transpose
// v [B*T][C] (col = h*64+d)  ->  vt [B][H][D][T].
__global__ __launch_bounds__(256) void transposeV(const __bf16* __restrict__ v,
                                                  __bf16* __restrict__ vt) {
  __shared__ __bf16 tile[64][72];
  const int t0 = blockIdx.x * 64;
  const int h = blockIdx.y, b = blockIdx.z;
  const int l = threadIdx.x;
  const int r = l >> 2, c8 = (l & 3) * 16;
  const __bf16* src = v + (size_t)(b * T_ + t0 + r) * C_ + h * 64 + c8;
  *reinterpret_cast<bf16x8*>(&tile[r][c8]) = *reinterpret_cast<const bf16x8*>(src);
  *reinterpret_cast<bf16x8*>(&tile[r][c8 + 8]) = *reinterpret_cast<const bf16x8*>(src + 8);
  __syncthreads();
  __bf16* dst = vt + (size_t)((b * H_ + h) * 64 + r) * T_ + t0 + c8;
  bf16x8 o0, o1;
#pragma unroll
  for (int i = 0; i < 8; ++i) { o0[i] = tile[c8 + i][r]; o1[i] = tile[c8 + 8 + i][r]; }
  *reinterpret_cast<bf16x8*>(dst) = o0;
  *reinterpret_cast<bf16x8*>(dst + 8) = o1;
}

// ---------------------------------------------------------------- helpers
__device__ __forceinline__ unsigned pk2(float a, float b) {
  const unsigned short ua = __builtin_bit_cast(unsigned short, (__bf16)a);
  const unsigned short ub = __builtin_bit_cast(unsigned short, (__bf16)b);
  return (unsigned)ua | ((unsigned)ub << 16);
}

// ---------------------------------------------------------------- flash attention v6
// R3 paired structure (uniform 65 tiles/wave, whole grid co-resident) + register
// double-buffered K/V prefetch (named vars + macros -> no scratch, rule #20).
// Layouts (R3-verified): swapped QK^T -> S^T col=q=lane31, row kv=(r&3)+8*(r>>2)+4*hi;
// P^T frags via shfl_xor(32); O^T = V^T * P^T from pre-transposed global V^T.

// load K/V fragments for tile TT into named buffer set SFX
#define LOADKV(SFX, TT)                                                          \
  do {                                                                           \
    const __bf16* kp_ = kb + (rowbase + (TT) * 32 + lane31) * C_ + hoff + hi * 8;\
    k##SFX##0 = *reinterpret_cast<const bf16x8*>(kp_);                           \
    k##SFX##1 = *reinterpret_cast<const bf16x8*>(kp_ + 16);                      \
    k##SFX##2 = *reinterpret_cast<const bf16x8*>(kp_ + 32);                      \
    k##SFX##3 = *reinterpret_cast<const bf16x8*>(kp_ + 48);                      \
    const __bf16* vp_ = vtb + (size_t)lane31 * T_ + (TT) * 32 + hi * 8;          \
    v##SFX##0 = *reinterpret_cast<const bf16x8*>(vp_);                           \
    v##SFX##1 = *reinterpret_cast<const bf16x8*>(vp_ + 16);                      \
    v##SFX##2 = *reinterpret_cast<const bf16x8*>(vp_ + 32 * T_);                 \
    v##SFX##3 = *reinterpret_cast<const bf16x8*>(vp_ + 32 * T_ + 16);            \
  } while (0)

#define TILE(SFX, MASKED)                                                        \
  do {                                                                           \
    f32x16 s = {};                                                               \
    __builtin_amdgcn_s_setprio(1);                                               \
    s = __builtin_amdgcn_mfma_f32_32x32x16_bf16(k##SFX##0, qf[0], s, 0, 0, 0);   \
    s = __builtin_amdgcn_mfma_f32_32x32x16_bf16(k##SFX##1, qf[1], s, 0, 0, 0);   \
    s = __builtin_amdgcn_mfma_f32_32x32x16_bf16(k##SFX##2, qf[2], s, 0, 0, 0);   \
    s = __builtin_amdgcn_mfma_f32_32x32x16_bf16(k##SFX##3, qf[3], s, 0, 0, 0);   \
    __builtin_amdgcn_s_setprio(0);                                               \
    float sv[16];                                                                \
    _Pragma("unroll") for (int r = 0; r < 16; ++r) sv[r] = s[r];                 \
    if (MASKED) {                                                                \
      _Pragma("unroll") for (int r = 0; r < 16; ++r) {                           \
        const int kvloc = (r & 3) + 8 * (r >> 2) + 4 * hi;                       \
        sv[r] = (kvloc <= lane31) ? sv[r] : -1e30f;                              \
      }                                                                          \
    }                                                                            \
    float a8[8];                                                                 \
    _Pragma("unroll") for (int r = 0; r < 8; ++r) a8[r] = fmaxf(sv[2 * r], sv[2 * r + 1]); \
    _Pragma("unroll") for (int r = 0; r < 4; ++r) a8[r] = fmaxf(a8[2 * r], a8[2 * r + 1]); \
    float mm = fmaxf(fmaxf(a8[0], a8[1]), fmaxf(a8[2], a8[3]));                  \
    mm = fmaxf(mm, __shfl_xor(mm, 32));                                          \
    if (mm > m_run + THRRAW) {                                                   \
      const float alpha = fexp2((m_run - mm) * K2);                              \
      _Pragma("unroll") for (int r = 0; r < 16; ++r) { acc0[r] *= alpha; acc1[r] *= alpha; } \
      l_run *= alpha;                                                            \
      m_run = mm;                                                                \
    }                                                                            \
    const float negm = -m_run * K2;                                              \
    _Pragma("unroll") for (int r = 0; r < 16; ++r)                               \
      sv[r] = fexp2(__builtin_fmaf(sv[r], K2, negm));                            \
    float b8[8];                                                                 \
    _Pragma("unroll") for (int r = 0; r < 8; ++r) b8[r] = sv[2 * r] + sv[2 * r + 1]; \
    _Pragma("unroll") for (int r = 0; r < 4; ++r) b8[r] = b8[2 * r] + b8[2 * r + 1]; \
    float rs = (b8[0] + b8[1]) + (b8[2] + b8[3]);                                \
    rs += __shfl_xor(rs, 32);                                                    \
    l_run += rs;                                                                 \
    unsigned pwv[8];                                                             \
    _Pragma("unroll") for (int ks = 0; ks < 2; ++ks) {                           \
      const unsigned X0 = pk2(sv[ks * 8 + 0], sv[ks * 8 + 1]);                   \
      const unsigned X1 = pk2(sv[ks * 8 + 2], sv[ks * 8 + 3]);                   \
      const unsigned Y0 = pk2(sv[ks * 8 + 4], sv[ks * 8 + 5]);                   \
      const unsigned Y1 = pk2(sv[ks * 8 + 6], sv[ks * 8 + 7]);                   \
      const unsigned sX0 = __shfl_xor(X0, 32);                                   \
      const unsigned sX1 = __shfl_xor(X1, 32);                                   \
      const unsigned sY0 = __shfl_xor(Y0, 32);                                   \
      const unsigned sY1 = __shfl_xor(Y1, 32);                                   \
      pwv[ks * 4 + 0] = hi ? sY0 : X0;                                           \
      pwv[ks * 4 + 1] = hi ? sY1 : X1;                                           \
      pwv[ks * 4 + 2] = hi ? Y0 : sX0;                                           \
      pwv[ks * 4 + 3] = hi ? Y1 : sX1;                                           \
    }                                                                            \
    const uint4v u0 = {pwv[0], pwv[1], pwv[2], pwv[3]};                          \
    const uint4v u1 = {pwv[4], pwv[5], pwv[6], pwv[7]};                          \
    const bf16x8 pf0 = __builtin_bit_cast(bf16x8, u0);                           \
    const bf16x8 pf1 = __builtin_bit_cast(bf16x8, u1);                           \
    __builtin_amdgcn_s_setprio(1);                                               \
    acc0 = __builtin_amdgcn_mfma_f32_32x32x16_bf16(v##SFX##0, pf0, acc0, 0, 0, 0); \
    acc0 = __builtin_amdgcn_mfma_f32_32x32x16_bf16(v##SFX##1, pf1, acc0, 0, 0, 0); \
    acc1 = __builtin_amdgcn_mfma_f32_32x32x16_bf16(v##SFX##2, pf0, acc1, 0, 0, 0); \
    acc1 = __builtin_amdgcn_mfma_f32_32x32x16_bf16(v##SFX##3, pf1, acc1, 0, 0, 0); \
    __builtin_amdgcn_s_setprio(0);                                               \
  } while (0)

__global__ __launch_bounds__(256) void attn_fwd(const __bf16* __restrict__ qb,
                                                const __bf16* __restrict__ kb,
                                                const __bf16* __restrict__ vt,
                                                __bf16* __restrict__ ao) {
  const int tid = threadIdx.x;
  const int w = tid >> 6, l = tid & 63;
  const int lane31 = l & 31, hi = l >> 5;
  const int b = blockIdx.y >> 4;
  const int qx = blockIdx.x * 4 + w;  // 0..31; paired with 63-qx => uniform 65 tiles
  const size_t rowbase = (size_t)b * T_;
  const int hoff = (blockIdx.y & 15) * D_;
  const __bf16* vtb = vt + (size_t)blockIdx.y * (size_t)(D_ * T_);
  const float K2 = 0.04508422f;   // C^-0.5 * log2(e)
  const float THRRAW = 177.0f;    // defer-max: exp2 arg <= 8 -> P <= 256

  for (int phase = 0; phase < 2; ++phase) {
    const int qg = (phase ? 63 - qx : qx) * 32;
    const int ntiles = (qg >> 5) + 1;

    bf16x8 qf[4];
    {
      const __bf16* qp = qb + (rowbase + qg + lane31) * C_ + hoff + hi * 8;
#pragma unroll
      for (int t4 = 0; t4 < 4; ++t4) qf[t4] = *reinterpret_cast<const bf16x8*>(qp + t4 * 16);
    }

    f32x16 acc0 = {};  // O^T rows d 0..31 (col = q = lane31)
    f32x16 acc1 = {};  // O^T rows d 32..63
    float m_run = -3.0e38f, l_run = 0.f;

    bf16x8 kA0, kA1, kA2, kA3, vA0, vA1, vA2, vA3;
    bf16x8 kB0, kB1, kB2, kB3, vB0, vB1, vB2, vB3;

    LOADKV(A, 0);
    int t = 0;
    for (; t + 1 < ntiles; ++t) {
      if ((t & 1) == 0) {
        LOADKV(B, t + 1);   // prefetch next tile while computing current
        TILE(A, false);
      } else {
        LOADKV(A, t + 1);
        TILE(B, false);
      }
    }
    if ((t & 1) == 0) TILE(A, true);
    else              TILE(B, true);

    // epilogue: O[q][d] = O^T[d][q]/l ; d = dblk*32 + qd*8 + hi*4 + j
    const float rl = 1.0f / l_run;
    __bf16* op = ao + (rowbase + qg + lane31) * C_ + hoff + hi * 4;
#pragma unroll
    for (int dblk = 0; dblk < 2; ++dblk)
#pragma unroll
      for (int qd = 0; qd < 4; ++qd) {
        bf16x4 ov;
#pragma unroll
        for (int j = 0; j < 4; ++j) {
          const float av = (dblk == 0) ? acc0[qd * 4 + j] : acc1[qd * 4 + j];
          ov[j] = (__bf16)(av * rl);
        }
        *reinterpret_cast<bf16x4*>(op + dblk * 32 + qd * 8) = ov;
      }
  }
}

// ---------------------------------------------------------------- launch
extern "C" void kernel_launch(void* const* d_in, const int* in_sizes, int n_in,
                              void* d_out, int out_size, void* d_ws, size_t ws_size,
                              hipStream_t stream) {
  const float* x  = (const float*)d_in[0];
  const float* Wq = (const float*)d_in[1];
  const float* Wk = (const float*)d_in[2];
  const float* Wv = (const float*)d_in[3];
  const float* Wp = (const float*)d_in[4];
  const float* bp = (const float*)d_in[5];
  float* out = (float*)d_out;

  const int NX = B_ * T_ * C_;
  const int NW = C_ * C_;

  __bf16* xb  = (__bf16*)d_ws;
  __bf16* wqb = xb + NX;
  __bf16* wkb = wqb + NW;
  __bf16* wvb = wkb + NW;
  __bf16* wpb = wvb + NW;
  __bf16* qb  = wpb + NW;
  __bf16* kb  = qb + NX;
  __bf16* vb  = kb + NX;
  __bf16* aob = vb + NX;
  __bf16* vtb = xb;  // xb dead after gemm_qkv; reuse as V^T [B][H][D][T]

  castk<<<NX / 1024, 256, 0, stream>>>(x, xb, NX);
  castk<<<NW / 1024, 256, 0, stream>>>(Wq, wqb, NW);
  castk<<<NW / 1024, 256, 0, stream>>>(Wk, wkb, NW);
  castk<<<NW / 1024, 256, 0, stream>>>(Wv, wvb, NW);
  castk<<<NW / 1024, 256, 0, stream>>>(Wp, wpb, NW);

  gemm_qkv<<<dim3(C_ / 128, (B_ * T_) / 128, 3), 256, 0, stream>>>(xb, wqb, wkb, wvb, qb, kb, vb);
  transposeV<<<dim3(T_ / 64, H_, B_), 256, 0, stream>>>(vb, vtb);
  attn_fwd<<<dim3(8, B_ * H_), 256, 0, stream>>>(qb, kb, vtb, aob);
  gemm_proj<<<dim3(C_ / 128, (B_ * T_) / 128), 256, 0, stream>>>(aob, wpb, out, bp);
}